// Round 9
// baseline (38.802 us; speedup 1.0000x reference)
//
#include <hip/hip_runtime.h>
#include <math.h>

#define EPS_F 1e-10f

typedef __attribute__((ext_vector_type(2))) float f2;
typedef __attribute__((ext_vector_type(2))) unsigned int u2;

typedef const __attribute__((address_space(1))) char* gcp;
typedef __attribute__((address_space(3))) char* lcp;

__device__ __forceinline__ f2 v_fabs(f2 x) {
  u2 u = __builtin_bit_cast(u2, x);
  u &= 0x7fffffffu;
  return __builtin_bit_cast(f2, u);
}
__device__ __forceinline__ f2 v_max(f2 a, f2 b) { return __builtin_elementwise_max(a, b); }
__device__ __forceinline__ f2 v_min(f2 a, f2 b) { return __builtin_elementwise_min(a, b); }
__device__ __forceinline__ f2 v_log(f2 x) {
  f2 r; r.x = __logf(x.x); r.y = __logf(x.y); return r;
}
__device__ __forceinline__ f2 v_rcp(f2 x) {
  f2 r; r.x = __builtin_amdgcn_rcpf(x.x); r.y = __builtin_amdgcn_rcpf(x.y); return r;
}
__device__ __forceinline__ f2 v_rsq(f2 x) {
  f2 r; r.x = __builtin_amdgcn_rsqf(x.x); r.y = __builtin_amdgcn_rsqf(x.y); return r;
}
__device__ __forceinline__ f2 v_sqrt(f2 x) {
  f2 r; r.x = __builtin_amdgcn_sqrtf(x.x); r.y = __builtin_amdgcn_sqrtf(x.y); return r;
}
__device__ __forceinline__ f2 v_cos(f2 x) {
  f2 r; r.x = __cosf(x.x); r.y = __cosf(x.y); return r;
}

// acos via minimax poly (|err| ~ 2e-8 rad)
__device__ __forceinline__ f2 v_acos(f2 r) {
  const f2 t = v_fabs(r);
  const f2 s = v_sqrt(1.0f - t);
  f2 p = f2{-0.0012624911f, -0.0012624911f};
  p = p * t +  0.0066700901f;
  p = p * t + -0.0170881256f;
  p = p * t +  0.0308918810f;
  p = p * t + -0.0501743046f;
  p = p * t +  0.0889789874f;
  p = p * t + -0.2145988016f;
  p = p * t +  1.5707963050f;
  const f2 ac = s * p;
  f2 res;
  res.x = (r.x < 0.0f) ? (3.14159265358979f - ac.x) : ac.x;
  res.y = (r.y < 0.0f) ? (3.14159265358979f - ac.y) : ac.y;
  return res;
}

// ||logm(D1)-logm(D2)||_F^2 for ONE matrix pair, packed .x=D1 .y=D2.
__device__ __forceinline__ float pair_loss(f2 a00, f2 a01, f2 a02,
                                           f2 a11, f2 a12, f2 a22) {
  a00 = v_fabs(a00); a01 = v_fabs(a01); a02 = v_fabs(a02);
  a11 = v_fabs(a11); a12 = v_fabs(a12); a22 = v_fabs(a22);

  const f2 q   = (a00 + a11 + a22) * (1.0f / 3.0f);
  const f2 b00 = a00 - q, b11 = a11 - q, b22 = a22 - q;
  const f2 p2  = b00 * b00 + b11 * b11 + b22 * b22 +
                 2.0f * (a01 * a01 + a02 * a02 + a12 * a12);

  const f2 p2c  = v_max(p2 * (1.0f / 6.0f), 1e-10f * q * q + 1e-35f);
  const f2 pinv = v_rsq(p2c);          // 1/p
  const f2 p    = p2c * pinv;          // sqrt(p2c)

  const f2 detB = b00 * (b11 * b22 - a12 * a12)
                - a01 * (a01 * b22 - a12 * a02)
                + a02 * (a01 * a12 - b11 * a02);
  f2 r = detB * 0.5f * pinv * pinv * pinv;
  r = v_min(f2{1.0f, 1.0f}, v_max(f2{-1.0f, -1.0f}, r));
  const f2 phi  = v_acos(r) * (1.0f / 3.0f);
  const f2 twop = 2.0f * p;
  const f2 l1 = q + twop * v_cos(phi);                          // largest
  const f2 l3 = q + twop * v_cos(phi + 2.0943951023931953f);    // smallest
  const f2 l2 = 3.0f * q - l1 - l3;

  const f2 s00 = a00 * a00 + a01 * a01 + a02 * a02;
  const f2 s01 = a00 * a01 + a01 * a11 + a02 * a12;
  const f2 s02 = a00 * a02 + a01 * a12 + a02 * a22;
  const f2 s11 = a01 * a01 + a11 * a11 + a12 * a12;
  const f2 s12 = a01 * a02 + a11 * a12 + a12 * a22;
  const f2 s22 = a02 * a02 + a12 * a12 + a22 * a22;

  const f2 g12 = l1 - l2, g23 = l2 - l3;
  f2 alpha, gamma;
  alpha.x = (g12.x >= g23.x) ? l1.x : l3.x;  gamma.x = (g12.x >= g23.x) ? l3.x : l1.x;
  alpha.y = (g12.y >= g23.y) ? l1.y : l3.y;  gamma.y = (g12.y >= g23.y) ? l3.y : l1.y;
  const f2 beta = l2;

  const f2 f_a = v_log(alpha + EPS_F);
  const f2 f_b = v_log(beta  + EPS_F);
  const f2 f_g = v_log(gamma + EPS_F);

  const f2 inv_den_a = v_rcp((alpha - beta) * (alpha - gamma));

  const f2 gap = gamma - beta;
  const f2 ga  = gamma - alpha;
  const f2 agap = v_fabs(gap);
  const f2 thr  = 1e-5f * v_max(v_fabs(beta), v_fabs(gamma));
  const f2 mid  = 0.5f * (beta + gamma) + EPS_F;
  f2 num, den;
  num.x = (agap.x > thr.x) ? (f_g.x - f_b.x) : 1.0f;
  den.x = (agap.x > thr.x) ? (gap.x * ga.x) : (mid.x * ga.x);
  num.y = (agap.y > thr.y) ? (f_g.y - f_b.y) : 1.0f;
  den.y = (agap.y > thr.y) ? (gap.y * ga.y) : (mid.y * ga.y);
  const f2 cg = num * v_rcp(den);
  const f2 wd = (f_a - f_b) * inv_den_a;

  // logm = c2*A^2 + c1*A + c0*I
  const f2 sbg = beta + gamma, pbg = beta * gamma;
  const f2 sab = alpha + beta, pab = alpha * beta;
  const f2 c2 = wd + cg;
  const f2 c1 = -(wd * sbg + cg * sab);
  const f2 c0 = f_b + wd * pbg + cg * pab;

  const f2 L0 = c2 * s00 + c1 * a00 + c0;
  const f2 L1 = c2 * s01 + c1 * a01;
  const f2 L2 = c2 * s02 + c1 * a02;
  const f2 L3 = c2 * s11 + c1 * a11 + c0;
  const f2 L4 = c2 * s12 + c1 * a12;
  const f2 L5 = c2 * s22 + c1 * a22 + c0;

  const float d0 = L0.x - L0.y;
  const float d1 = L1.x - L1.y;
  const float d2 = L2.x - L2.y;
  const float d3 = L3.x - L3.y;
  const float d4 = L4.x - L4.y;
  const float d5 = L5.x - L5.y;
  return d0 * d0 + d3 * d3 + d5 * d5 + 2.0f * (d1 * d1 + d2 * d2 + d4 * d4);
}

// Per wave: 64 pairs, 2304 B per tensor, staged densely into a private LDS
// slice (d1 bytes [0,2304), d2 bytes [2304,4608)) with NO barriers.
#define WAVE_BYTES 4608
#define T_BYTES    2304          // per-tensor bytes per wave (64 * 36)

__global__ void __launch_bounds__(256, 8)
leloss_partial(const float* __restrict__ d1, const float* __restrict__ d2,
               float* __restrict__ partial, int nmat) {
  __shared__ float lds[4 * WAVE_BYTES / 4];   // 18432 B: 4 wave slices

  const int tid  = threadIdx.x;
  const int lane = tid & 63;
  const int wid  = tid >> 6;
  const int wgid = blockIdx.x * 4 + wid;      // global wave id
  const int p0   = wgid * 64;                 // first pair of this wave

  float acc = 0.0f;

  if (p0 + 64 <= nmat) {
    // ---- dense staging: 4 x width16 + 2 x width4 global_load_lds ----
    const char* s1 = reinterpret_cast<const char*>(d1) + (size_t)p0 * 36;
    const char* s2 = reinterpret_cast<const char*>(d2) + (size_t)p0 * 36;
    char* lbase = reinterpret_cast<char*>(lds) + wid * WAVE_BYTES;

#pragma unroll
    for (int j = 0; j < 4; ++j) {
      const int o = j * 1024 + lane * 16;     // byte offset in wave region
      const char* src = (o < T_BYTES) ? (s1 + o) : (s2 + (o - T_BYTES));
      __builtin_amdgcn_global_load_lds((gcp)src, (lcp)(lbase + o), 16, 0, 0);
    }
#pragma unroll
    for (int j = 0; j < 2; ++j) {
      const int o = 4096 + j * 256 + lane * 4;  // all >= T_BYTES -> d2
      const char* src = s2 + (o - T_BYTES);
      __builtin_amdgcn_global_load_lds((gcp)src, (lcp)(lbase + o), 4, 0, 0);
    }
    asm volatile("s_waitcnt vmcnt(0)" ::: "memory");

    // ---- per-thread gather from own wave slice (dword stride 9: 2-way max) ----
    const float* m1 = lds + wid * (WAVE_BYTES / 4) + lane * 9;
    const float* m2 = m1 + (T_BYTES / 4);
    const f2 a00 = f2{m1[0], m2[0]};
    const f2 a01 = f2{m1[1], m2[1]};
    const f2 a02 = f2{m1[2], m2[2]};
    const f2 a11 = f2{m1[4], m2[4]};
    const f2 a12 = f2{m1[5], m2[5]};
    const f2 a22 = f2{m1[8], m2[8]};
    acc = pair_loss(a00, a01, a02, a11, a12, a22);
  } else {
    // tail wave: direct guarded global loads (rare)
    const int pr = p0 + lane;
    if (pr < nmat) {
      const size_t base = (size_t)pr * 9;
      const f2 a00 = f2{d1[base + 0], d2[base + 0]};
      const f2 a01 = f2{d1[base + 1], d2[base + 1]};
      const f2 a02 = f2{d1[base + 2], d2[base + 2]};
      const f2 a11 = f2{d1[base + 4], d2[base + 4]};
      const f2 a12 = f2{d1[base + 5], d2[base + 5]};
      const f2 a22 = f2{d1[base + 8], d2[base + 8]};
      acc = pair_loss(a00, a01, a02, a11, a12, a22);
    }
  }

  // wave reduce (64 lanes)
#pragma unroll
  for (int off = 32; off > 0; off >>= 1) acc += __shfl_down(acc, off, 64);

  __shared__ float wsum[4];
  if ((tid & 63) == 0) wsum[wid] = acc;
  __syncthreads();
  if (tid == 0) {
    partial[blockIdx.x] = wsum[0] + wsum[1] + wsum[2] + wsum[3];
  }
}

__global__ void __launch_bounds__(256)
leloss_reduce(const float* __restrict__ partial, int n,
              float* __restrict__ out, double inv_count) {
  double s = 0.0;
  for (int i = threadIdx.x; i < n; i += 256) s += (double)partial[i];
#pragma unroll
  for (int off = 32; off > 0; off >>= 1) s += __shfl_down(s, off, 64);

  __shared__ double wsum[4];
  const int lane = threadIdx.x & 63;
  const int wid  = threadIdx.x >> 6;
  if (lane == 0) wsum[wid] = s;
  __syncthreads();
  if (threadIdx.x == 0) {
    const double total = wsum[0] + wsum[1] + wsum[2] + wsum[3];
    out[0] = (float)(total * inv_count);
  }
}

extern "C" void kernel_launch(void* const* d_in, const int* in_sizes, int n_in,
                              void* d_out, int out_size, void* d_ws, size_t ws_size,
                              hipStream_t stream) {
  const float* d1 = (const float*)d_in[0];
  const float* d2 = (const float*)d_in[1];
  float* out = (float*)d_out;
  float* partial = (float*)d_ws;

  const long long nelem = (long long)in_sizes[0];
  const int nmat = (int)(nelem / 9);
  const int nblocks = (nmat + 255) / 256;       // 256 pairs per block (4 waves)

  leloss_partial<<<nblocks, 256, 0, stream>>>(d1, d2, partial, nmat);

  const double inv_count = 1.0 / ((double)nmat * 9.0);
  leloss_reduce<<<1, 256, 0, stream>>>(partial, nblocks, out, inv_count);
}

// Round 10
// 34.247 us; speedup vs baseline: 1.1330x; 1.1330x over previous
//
#include <hip/hip_runtime.h>
#include <math.h>

#define EPS_F 1e-10f

typedef __attribute__((ext_vector_type(2))) float f2;
typedef __attribute__((ext_vector_type(2))) unsigned int u2;

typedef const __attribute__((address_space(1))) char* gcp;
typedef __attribute__((address_space(3))) char* lcp;

__device__ __forceinline__ f2 v_fabs(f2 x) {
  u2 u = __builtin_bit_cast(u2, x);
  u &= 0x7fffffffu;
  return __builtin_bit_cast(f2, u);
}
__device__ __forceinline__ f2 v_max(f2 a, f2 b) { return __builtin_elementwise_max(a, b); }
__device__ __forceinline__ f2 v_min(f2 a, f2 b) { return __builtin_elementwise_min(a, b); }
__device__ __forceinline__ f2 v_log(f2 x) {
  f2 r; r.x = __logf(x.x); r.y = __logf(x.y); return r;
}
__device__ __forceinline__ f2 v_rcp(f2 x) {
  f2 r; r.x = __builtin_amdgcn_rcpf(x.x); r.y = __builtin_amdgcn_rcpf(x.y); return r;
}
__device__ __forceinline__ f2 v_rsq(f2 x) {
  f2 r; r.x = __builtin_amdgcn_rsqf(x.x); r.y = __builtin_amdgcn_rsqf(x.y); return r;
}
__device__ __forceinline__ f2 v_sqrt(f2 x) {
  f2 r; r.x = __builtin_amdgcn_sqrtf(x.x); r.y = __builtin_amdgcn_sqrtf(x.y); return r;
}
__device__ __forceinline__ f2 v_cos(f2 x) {
  f2 r; r.x = __cosf(x.x); r.y = __cosf(x.y); return r;
}

// acos via minimax poly (|err| ~ 2e-8 rad)
__device__ __forceinline__ f2 v_acos(f2 r) {
  const f2 t = v_fabs(r);
  const f2 s = v_sqrt(1.0f - t);
  f2 p = f2{-0.0012624911f, -0.0012624911f};
  p = p * t +  0.0066700901f;
  p = p * t + -0.0170881256f;
  p = p * t +  0.0308918810f;
  p = p * t + -0.0501743046f;
  p = p * t +  0.0889789874f;
  p = p * t + -0.2145988016f;
  p = p * t +  1.5707963050f;
  const f2 ac = s * p;
  f2 res;
  res.x = (r.x < 0.0f) ? (3.14159265358979f - ac.x) : ac.x;
  res.y = (r.y < 0.0f) ? (3.14159265358979f - ac.y) : ac.y;
  return res;
}

// ||logm(D1)-logm(D2)||_F^2 for ONE matrix pair, packed .x=D1 .y=D2.
__device__ __forceinline__ float pair_loss(f2 a00, f2 a01, f2 a02,
                                           f2 a11, f2 a12, f2 a22) {
  a00 = v_fabs(a00); a01 = v_fabs(a01); a02 = v_fabs(a02);
  a11 = v_fabs(a11); a12 = v_fabs(a12); a22 = v_fabs(a22);

  const f2 q   = (a00 + a11 + a22) * (1.0f / 3.0f);
  const f2 b00 = a00 - q, b11 = a11 - q, b22 = a22 - q;
  const f2 p2  = b00 * b00 + b11 * b11 + b22 * b22 +
                 2.0f * (a01 * a01 + a02 * a02 + a12 * a12);

  const f2 p2c  = v_max(p2 * (1.0f / 6.0f), 1e-10f * q * q + 1e-35f);
  const f2 pinv = v_rsq(p2c);          // 1/p
  const f2 p    = p2c * pinv;          // sqrt(p2c)

  const f2 detB = b00 * (b11 * b22 - a12 * a12)
                - a01 * (a01 * b22 - a12 * a02)
                + a02 * (a01 * a12 - b11 * a02);
  f2 r = detB * 0.5f * pinv * pinv * pinv;
  r = v_min(f2{1.0f, 1.0f}, v_max(f2{-1.0f, -1.0f}, r));
  const f2 phi  = v_acos(r) * (1.0f / 3.0f);
  const f2 twop = 2.0f * p;
  const f2 l1 = q + twop * v_cos(phi);                          // largest
  const f2 l3 = q + twop * v_cos(phi + 2.0943951023931953f);    // smallest
  const f2 l2 = 3.0f * q - l1 - l3;

  const f2 s00 = a00 * a00 + a01 * a01 + a02 * a02;
  const f2 s01 = a00 * a01 + a01 * a11 + a02 * a12;
  const f2 s02 = a00 * a02 + a01 * a12 + a02 * a22;
  const f2 s11 = a01 * a01 + a11 * a11 + a12 * a12;
  const f2 s12 = a01 * a02 + a11 * a12 + a12 * a22;
  const f2 s22 = a02 * a02 + a12 * a12 + a22 * a22;

  const f2 g12 = l1 - l2, g23 = l2 - l3;
  f2 alpha, gamma;
  alpha.x = (g12.x >= g23.x) ? l1.x : l3.x;  gamma.x = (g12.x >= g23.x) ? l3.x : l1.x;
  alpha.y = (g12.y >= g23.y) ? l1.y : l3.y;  gamma.y = (g12.y >= g23.y) ? l3.y : l1.y;
  const f2 beta = l2;

  const f2 f_a = v_log(alpha + EPS_F);
  const f2 f_b = v_log(beta  + EPS_F);
  const f2 f_g = v_log(gamma + EPS_F);

  const f2 inv_den_a = v_rcp((alpha - beta) * (alpha - gamma));

  const f2 gap = gamma - beta;
  const f2 ga  = gamma - alpha;
  const f2 agap = v_fabs(gap);
  const f2 thr  = 1e-5f * v_max(v_fabs(beta), v_fabs(gamma));
  const f2 mid  = 0.5f * (beta + gamma) + EPS_F;
  f2 num, den;
  num.x = (agap.x > thr.x) ? (f_g.x - f_b.x) : 1.0f;
  den.x = (agap.x > thr.x) ? (gap.x * ga.x) : (mid.x * ga.x);
  num.y = (agap.y > thr.y) ? (f_g.y - f_b.y) : 1.0f;
  den.y = (agap.y > thr.y) ? (gap.y * ga.y) : (mid.y * ga.y);
  const f2 cg = num * v_rcp(den);
  const f2 wd = (f_a - f_b) * inv_den_a;

  // logm = c2*A^2 + c1*A + c0*I
  const f2 sbg = beta + gamma, pbg = beta * gamma;
  const f2 sab = alpha + beta, pab = alpha * beta;
  const f2 c2 = wd + cg;
  const f2 c1 = -(wd * sbg + cg * sab);
  const f2 c0 = f_b + wd * pbg + cg * pab;

  const f2 L0 = c2 * s00 + c1 * a00 + c0;
  const f2 L1 = c2 * s01 + c1 * a01;
  const f2 L2 = c2 * s02 + c1 * a02;
  const f2 L3 = c2 * s11 + c1 * a11 + c0;
  const f2 L4 = c2 * s12 + c1 * a12;
  const f2 L5 = c2 * s22 + c1 * a22 + c0;

  const float d0 = L0.x - L0.y;
  const float d1 = L1.x - L1.y;
  const float d2 = L2.x - L2.y;
  const float d3 = L3.x - L3.y;
  const float d4 = L4.x - L4.y;
  const float d5 = L5.x - L5.y;
  return d0 * d0 + d3 * d3 + d5 * d5 + 2.0f * (d1 * d1 + d2 * d2 + d4 * d4);
}

// chunk = 64 pairs; per-tensor bytes per chunk = 64*36 = 2304; both = 4608.
#define CH_T_BYTES 2304
#define CH_BYTES   4608
#define SLICES_PER_WAVE 2                 // double buffer
#define WAVE_LDS (CH_BYTES * SLICES_PER_WAVE)   // 9216 B
#define BLOCK_LDS (WAVE_LDS * 4)                // 36864 B

__global__ void __launch_bounds__(256, 4)
leloss_partial(const float* __restrict__ d1, const float* __restrict__ d2,
               float* __restrict__ partial, int nmat) {
  __shared__ float lds[BLOCK_LDS / 4];

  const int tid  = threadIdx.x;
  const int lane = tid & 63;
  const int wid  = tid >> 6;
  const int wgid = blockIdx.x * 4 + wid;       // global wave id
  const int p0   = wgid * 128;                  // first pair (2 chunks of 64)
  const int p1   = p0 + 64;

  char* lb0 = reinterpret_cast<char*>(lds) + wid * WAVE_LDS;
  char* lb1 = lb0 + CH_BYTES;

  float acc = 0.0f;

  if (p1 + 64 <= nmat) {
    const char* base1 = reinterpret_cast<const char*>(d1);
    const char* base2 = reinterpret_cast<const char*>(d2);

    // ---- stage chunk 0 then chunk 1 (6 VMEM ops each), no waits yet ----
#pragma unroll
    for (int s = 0; s < 2; ++s) {
      const size_t gb = (size_t)(s == 0 ? p0 : p1) * 36;
      char* lb = (s == 0) ? lb0 : lb1;
#pragma unroll
      for (int j = 0; j < 4; ++j) {
        const int o = j * 1024 + lane * 16;
        const char* src = (o < CH_T_BYTES) ? (base1 + gb + o)
                                           : (base2 + gb + (o - CH_T_BYTES));
        __builtin_amdgcn_global_load_lds((gcp)src, (lcp)(lb + o), 16, 0, 0);
      }
#pragma unroll
      for (int j = 0; j < 2; ++j) {
        const int o = 4096 + j * 256 + lane * 4;
        __builtin_amdgcn_global_load_lds((gcp)(base2 + gb + (o - CH_T_BYTES)),
                                         (lcp)(lb + o), 4, 0, 0);
      }
    }

    // ---- chunk 0 ready (6 oldest retired); chunk 1 still in flight ----
    asm volatile("s_waitcnt vmcnt(6)" ::: "memory");
    {
      const float* m1 = reinterpret_cast<const float*>(lb0) + lane * 9;
      const float* m2 = reinterpret_cast<const float*>(lb0 + CH_T_BYTES) + lane * 9;
      const f2 a00 = f2{m1[0], m2[0]};
      const f2 a01 = f2{m1[1], m2[1]};
      const f2 a02 = f2{m1[2], m2[2]};
      const f2 a11 = f2{m1[4], m2[4]};
      const f2 a12 = f2{m1[5], m2[5]};
      const f2 a22 = f2{m1[8], m2[8]};
      acc = pair_loss(a00, a01, a02, a11, a12, a22);
    }

    // ---- chunk 1 (latency hidden under chunk-0 compute) ----
    asm volatile("s_waitcnt vmcnt(0)" ::: "memory");
    {
      const float* m1 = reinterpret_cast<const float*>(lb1) + lane * 9;
      const float* m2 = reinterpret_cast<const float*>(lb1 + CH_T_BYTES) + lane * 9;
      const f2 a00 = f2{m1[0], m2[0]};
      const f2 a01 = f2{m1[1], m2[1]};
      const f2 a02 = f2{m1[2], m2[2]};
      const f2 a11 = f2{m1[4], m2[4]};
      const f2 a12 = f2{m1[5], m2[5]};
      const f2 a22 = f2{m1[8], m2[8]};
      acc += pair_loss(a00, a01, a02, a11, a12, a22);
    }
  } else {
    // tail waves: guarded direct global loads (not taken for this size)
#pragma unroll
    for (int s = 0; s < 2; ++s) {
      const int pr = (s == 0 ? p0 : p1) + lane;
      if (pr < nmat) {
        const size_t base = (size_t)pr * 9;
        const f2 a00 = f2{d1[base + 0], d2[base + 0]};
        const f2 a01 = f2{d1[base + 1], d2[base + 1]};
        const f2 a02 = f2{d1[base + 2], d2[base + 2]};
        const f2 a11 = f2{d1[base + 4], d2[base + 4]};
        const f2 a12 = f2{d1[base + 5], d2[base + 5]};
        const f2 a22 = f2{d1[base + 8], d2[base + 8]};
        acc += pair_loss(a00, a01, a02, a11, a12, a22);
      }
    }
  }

  // wave reduce (64 lanes)
#pragma unroll
  for (int off = 32; off > 0; off >>= 1) acc += __shfl_down(acc, off, 64);

  __shared__ float wsum[4];
  if (lane == 0) wsum[wid] = acc;
  __syncthreads();
  if (tid == 0) {
    partial[blockIdx.x] = wsum[0] + wsum[1] + wsum[2] + wsum[3];
  }
}

__global__ void __launch_bounds__(256)
leloss_reduce(const float* __restrict__ partial, int n,
              float* __restrict__ out, double inv_count) {
  double s = 0.0;
  for (int i = threadIdx.x; i < n; i += 256) s += (double)partial[i];
#pragma unroll
  for (int off = 32; off > 0; off >>= 1) s += __shfl_down(s, off, 64);

  __shared__ double wsum[4];
  const int lane = threadIdx.x & 63;
  const int wid  = threadIdx.x >> 6;
  if (lane == 0) wsum[wid] = s;
  __syncthreads();
  if (threadIdx.x == 0) {
    const double total = wsum[0] + wsum[1] + wsum[2] + wsum[3];
    out[0] = (float)(total * inv_count);
  }
}

extern "C" void kernel_launch(void* const* d_in, const int* in_sizes, int n_in,
                              void* d_out, int out_size, void* d_ws, size_t ws_size,
                              hipStream_t stream) {
  const float* d1 = (const float*)d_in[0];
  const float* d2 = (const float*)d_in[1];
  float* out = (float*)d_out;
  float* partial = (float*)d_ws;

  const long long nelem = (long long)in_sizes[0];
  const int nmat = (int)(nelem / 9);
  const int nblocks = (nmat + 511) / 512;   // 512 pairs per block (4 waves x 2 chunks)

  leloss_partial<<<nblocks, 256, 0, stream>>>(d1, d2, partial, nmat);

  const double inv_count = 1.0 / ((double)nmat * 9.0);
  leloss_reduce<<<1, 256, 0, stream>>>(partial, nblocks, out, inv_count);
}